// Round 2
// baseline (5269.485 us; speedup 1.0000x reference)
//
#include <hip/hip_runtime.h>

#define NN 200000
#define NE 600000
#define DD 128
#define DXX 3
#define DMM 256
#define NLVL 16
#define MAXLVL 16384   // max nodes per level (true ~12500, Binomial(200k,1/16))

// ---- workspace byte offsets (total ~115.6 MB) ----
#define OFF_H      0LL                      // float h[NN][128]         102,400,000
#define OFF_SC     102400000LL              // float s_c[MAXLVL][128]     8,388,608
#define OFF_DEG    110788608LL              // float deg_c[MAXLVL]           65,536
#define OFF_NLIST  110854144LL              // int node_list[NN]            800,000
#define OFF_NPOS   111654144LL              // int node_pos[NN]             800,000
#define OFF_ELIST  112454144LL              // int edge_list[NE]          2,400,000
#define OFF_WCT    114854144LL              // float WcT[128][384]          196,608
#define OFF_WHHT   115050752LL              // float whhT[128][384]         196,608
#define OFF_MB     115247360LL              // float mb[384]                  1,536
#define OFF_W1T    115248896LL              // float W1T[128][256]          131,072
#define OFF_W2T    115379968LL              // float W2T[256][256]          262,144
#define OFF_CNT    115642112LL              // int counters[128]                512
#define WS_NEEDED  115642624LL

// counter layout: [0..15] node_cnt  [16..31] edge_cnt
//                 [32..48] node_start(17)  [49..65] edge_start(17)
//                 [66..81] node_cur  [82..97] edge_cur

__device__ __forceinline__ float sigm(float x){
  x = fminf(fmaxf(x, -30.f), 30.f);
  return 1.f/(1.f + __expf(-x));
}
__device__ __forceinline__ float tanh_(float x){
  x = fminf(fmaxf(x, -15.f), 15.f);
  float e = __expf(2.f*x);
  return (e - 1.f)/(e + 1.f);
}

__global__ void k_zero_cnt(int* cnt){
  if (threadIdx.x < 128) cnt[threadIdx.x] = 0;
}

// h[v][d] = W_emd[d] + b_emd[d] for all v
__global__ void k_init_h(float* h, const float* W_emd, const float* b_emd){
  __shared__ float h0[DD];
  if (threadIdx.x < DD) h0[threadIdx.x] = W_emd[threadIdx.x] + b_emd[threadIdx.x];
  __syncthreads();
  const int tot = NN*DD/4;
  for (int i = blockIdx.x*blockDim.x + threadIdx.x; i < tot; i += gridDim.x*blockDim.x){
    int d0 = (i & 31)*4;
    ((float4*)h)[i] = make_float4(h0[d0], h0[d0+1], h0[d0+2], h0[d0+3]);
  }
}

// histogram nodes by level, edges by dst level
__global__ void k_count(const int* fl, const int* dst, int* cnt){
  __shared__ int hn[NLVL], he[NLVL];
  if (threadIdx.x < NLVL){ hn[threadIdx.x]=0; he[threadIdx.x]=0; }
  __syncthreads();
  const int tot = NN + NE;
  for (int i = blockIdx.x*blockDim.x + threadIdx.x; i < tot; i += gridDim.x*blockDim.x){
    if (i < NN) atomicAdd(&hn[fl[i]], 1);
    else        atomicAdd(&he[fl[dst[i-NN]]], 1);
  }
  __syncthreads();
  if (threadIdx.x < NLVL){
    if (hn[threadIdx.x]) atomicAdd(&cnt[threadIdx.x], hn[threadIdx.x]);
    if (he[threadIdx.x]) atomicAdd(&cnt[16+threadIdx.x], he[threadIdx.x]);
  }
}

__global__ void k_scan(int* cnt){
  if (threadIdx.x == 0){
    int s = 0;
    for (int l=0;l<NLVL;l++){ cnt[32+l] = s; s += cnt[l]; }
    cnt[48] = s;
    s = 0;
    for (int l=0;l<NLVL;l++){ cnt[49+l] = s; s += cnt[16+l]; }
    cnt[65] = s;
    for (int l=0;l<NLVL;l++){ cnt[66+l]=0; cnt[82+l]=0; }
  }
}

__global__ void k_fill(const int* fl, const int* dst, int* cnt,
                       int* node_list, int* node_pos, int* edge_list){
  const int tot = NN + NE;
  for (int i = blockIdx.x*blockDim.x + threadIdx.x; i < tot; i += gridDim.x*blockDim.x){
    if (i < NN){
      int l = fl[i];
      int p = atomicAdd(&cnt[66+l], 1);
      node_list[cnt[32+l] + p] = i;
      node_pos[i] = (p < MAXLVL) ? p : (MAXLVL-1);  // clamp: OOB-safe
    } else {
      int e = i - NN;
      int l = fl[dst[e]];
      int p = atomicAdd(&cnt[82+l], 1);
      edge_list[cnt[49+l] + p] = e;
    }
  }
}

// Precompute WcT[k][r] = sum_j w_ih[r][j]*W_aggr[j][k]; whhT; mb; W1T; W2T
__global__ void k_prep(const float* w_ih, const float* W_aggr, const float* b_aggr,
                       const float* w_hh, const float* W1, const float* W2,
                       float* WcT, float* whhT, float* mb, float* W1T, float* W2T){
  const int tid = blockIdx.x*blockDim.x + threadIdx.x;
  const int stride = gridDim.x*blockDim.x;
  for (int i = tid; i < 384*DD; i += stride){
    int r = i >> 7, k = i & (DD-1);
    float s = 0.f;
    for (int j=0;j<DD;j++) s += w_ih[r*(DD+DXX)+j]*W_aggr[j*DD+k];
    WcT[k*384 + r] = s;
  }
  for (int i = tid; i < 384*DD; i += stride){
    int r = i >> 7, k = i & (DD-1);
    whhT[k*384 + r] = w_hh[r*DD + k];
  }
  for (int i = tid; i < 384; i += stride){
    float s = 0.f;
    for (int j=0;j<DD;j++) s += w_ih[i*(DD+DXX)+j]*b_aggr[j];
    mb[i] = s;
  }
  for (int i = tid; i < DD*DMM; i += stride){
    int m = i & (DMM-1), k = i >> 8;
    W1T[k*DMM + m] = W1[m*DD + k];
  }
  for (int i = tid; i < DMM*DMM; i += stride){
    int m = i & (DMM-1), k = i >> 8;
    W2T[k*DMM + m] = W2[m*DMM + k];
  }
}

__global__ void k_zero_s(const int* cnt, int l, float* s_c, float* deg_c){
  int na = cnt[32+l+1] - cnt[32+l];
  if (na > MAXLVL) na = MAXLVL;
  const int tot = na*DD;
  const int stride = gridDim.x*blockDim.x;
  for (int i = blockIdx.x*blockDim.x + threadIdx.x; i < tot; i += stride) s_c[i] = 0.f;
  for (int i = blockIdx.x*blockDim.x + threadIdx.x; i < na;  i += stride) deg_c[i] = 0.f;
}

// scatter-add h[src] into compact s_c rows (dst nodes of this level)
__global__ void k_scatter(const int* cnt, int l, const int* edge_list,
                          const int* srcp, const int* dstp, const int* node_pos,
                          const float* h, float* s_c, float* deg_c){
  const int e0 = cnt[49+l];
  const int ne = cnt[49+l+1] - e0;
  const int tot = ne*DD;
  const int stride = gridDim.x*blockDim.x;
  for (int i = blockIdx.x*blockDim.x + threadIdx.x; i < tot; i += stride){
    int ei = i >> 7, d = i & (DD-1);
    int e  = edge_list[e0 + ei];
    int sv = srcp[e], dv = dstp[e];
    atomicAdd(&s_c[node_pos[dv]*DD + d], h[sv*DD + d]);
    if (d == 0) atomicAdd(&deg_c[node_pos[dv]], 1.f);
  }
}

// GRU update for the level's nodes. 32 nodes/block, 256 threads.
// thread t: j = t&127 (hidden index), g = t>>7 handles nodes {2n+g}.
#define GTM 32
__global__ __launch_bounds__(256) void k_gru(const int* cnt, int l,
    const int* node_list, const float* s_c, const float* deg_c,
    const float* x, const float* WcT, const float* whhT, const float* mb,
    const float* w_ih, const float* b_ih, const float* b_hh, float* h){
  const int n0 = cnt[32+l];
  int na = cnt[32+l+1] - n0;
  if (na > MAXLVL) na = MAXLVL;
  if (na <= 0) return;
  const int ntiles = (na + GTM-1)/GTM;
  __shared__ float s_l[GTM][DD];
  __shared__ float h_l[GTM][DD];
  __shared__ float x_l[GTM][4];
  __shared__ float deg_l[GTM];
  __shared__ int   vidx[GTM];
  const int t  = threadIdx.x;
  const int jt = t & (DD-1);
  const int g  = t >> 7;
  for (int tile = blockIdx.x; tile < ntiles; tile += gridDim.x){
    const int tb = tile*GTM;
    if (t < GTM){
      int v = (tb + t < na) ? node_list[n0 + tb + t] : -1;
      vidx[t] = v;
      deg_l[t] = (tb + t < na) ? deg_c[tb + t] : 0.f;
      for (int kx=0; kx<DXX; kx++) x_l[t][kx] = (v >= 0) ? x[v*DXX + kx] : 0.f;
    }
    for (int i = t; i < GTM*DD; i += 256){
      int j = i >> 7, k = i & (DD-1);
      int row = tb + j;
      float sv = 0.f, hv = 0.f;
      if (row < na){
        sv = s_c[row*DD + k];
        hv = h[node_list[n0 + row]*DD + k];
      }
      s_l[j][k] = sv;
      h_l[j][k] = hv;
    }
    __syncthreads();

    float agr[16], agz[16], agn[16], ahr[16], ahz[16], ahn[16];
    #pragma unroll
    for (int n=0;n<16;n++){ agr[n]=0.f; agz[n]=0.f; agn[n]=0.f; ahr[n]=0.f; ahz[n]=0.f; ahn[n]=0.f; }

    #pragma unroll 2
    for (int k=0;k<DD;k++){
      float w1 = WcT[k*384 + jt];
      float w2 = WcT[k*384 + 128 + jt];
      float w3 = WcT[k*384 + 256 + jt];
      float u1 = whhT[k*384 + jt];
      float u2 = whhT[k*384 + 128 + jt];
      float u3 = whhT[k*384 + 256 + jt];
      #pragma unroll
      for (int n=0;n<16;n++){
        int node = 2*n + g;
        float sv = s_l[node][k];
        float hv = h_l[node][k];
        agr[n] = fmaf(w1, sv, agr[n]);
        agz[n] = fmaf(w2, sv, agz[n]);
        agn[n] = fmaf(w3, sv, agn[n]);
        ahr[n] = fmaf(u1, hv, ahr[n]);
        ahz[n] = fmaf(u2, hv, ahz[n]);
        ahn[n] = fmaf(u3, hv, ahn[n]);
      }
    }
    // x part (feeds gi only)
    #pragma unroll
    for (int kx=0;kx<DXX;kx++){
      float wx1 = w_ih[jt*(DD+DXX) + DD + kx];
      float wx2 = w_ih[(128+jt)*(DD+DXX) + DD + kx];
      float wx3 = w_ih[(256+jt)*(DD+DXX) + DD + kx];
      #pragma unroll
      for (int n=0;n<16;n++){
        int node = 2*n + g;
        float xv = x_l[node][kx];
        agr[n] = fmaf(wx1, xv, agr[n]);
        agz[n] = fmaf(wx2, xv, agz[n]);
        agn[n] = fmaf(wx3, xv, agn[n]);
      }
    }
    float bi1 = b_ih[jt], bi2 = b_ih[128+jt], bi3 = b_ih[256+jt];
    float bh1 = b_hh[jt], bh2 = b_hh[128+jt], bh3 = b_hh[256+jt];
    float m1 = mb[jt], m2 = mb[128+jt], m3 = mb[256+jt];
    #pragma unroll
    for (int n=0;n<16;n++){
      int node = 2*n + g;
      int v = vidx[node];
      if (v < 0) continue;
      float dg = deg_l[node];
      float gr = agr[n] + bi1 + dg*m1 + ahr[n] + bh1;
      float gz = agz[n] + bi2 + dg*m2 + ahz[n] + bh2;
      float rr = sigm(gr);
      float zz = sigm(gz);
      float gn = agn[n] + bi3 + dg*m3 + rr*(ahn[n] + bh3);
      float nv = tanh_(gn);
      float hv = h_l[node][jt];
      h[v*DD + jt] = (1.f - zz)*nv + zz*hv;
    }
    __syncthreads();
  }
}

// fused MLP: h(128) -> relu 256 -> relu 256 -> 1. 32 nodes/block, 256 threads,
// register tile 4 nodes x 8 outputs. Weights staged to LDS in 16-row K tiles.
#define MTM 32
#define HTP 36
__global__ __launch_bounds__(256) void k_mlp(const float* h,
    const float* W1T, const float* b1, const float* W2T, const float* b2,
    const float* W3, const float* b3, float* out){
  __shared__ __align__(16) float hT[DD][HTP];    // 18.4 KB  (hT[k][n])
  __shared__ __align__(16) float h1T[DMM][HTP];  // 36.9 KB  (h1T[m][n])
  __shared__ __align__(16) float wT[16][DMM];    // 16.4 KB
  __shared__ float red[MTM][33];                 // 4.2 KB
  const int t  = threadIdx.x;
  const int tn = t & 7;    // 4 nodes: 4*tn..4*tn+3
  const int tm = t >> 3;   // 8 outputs: 8*tm..8*tm+7
  const int base = blockIdx.x*MTM;

  for (int i = t; i < MTM*DD; i += 256){
    int n = i >> 7, k = i & (DD-1);
    int v = base + n;
    hT[k][n] = (v < NN) ? h[v*DD + k] : 0.f;
  }
  __syncthreads();

  float acc[4][8];
  #pragma unroll
  for (int a=0;a<4;a++)
    #pragma unroll
    for (int b=0;b<8;b++) acc[a][b] = 0.f;

  // layer 1: K = 128
  for (int kt = 0; kt < DD; kt += 16){
    for (int i = t; i < 16*DMM; i += 256){
      int kk = i >> 8, m = i & (DMM-1);
      wT[kk][m] = W1T[(kt+kk)*DMM + m];
    }
    __syncthreads();
    #pragma unroll
    for (int kk=0; kk<16; kk++){
      float4 a4  = *(const float4*)&hT[kt+kk][4*tn];
      float4 w4a = *(const float4*)&wT[kk][8*tm];
      float4 w4b = *(const float4*)&wT[kk][8*tm+4];
      float av[4] = {a4.x, a4.y, a4.z, a4.w};
      float wv[8] = {w4a.x, w4a.y, w4a.z, w4a.w, w4b.x, w4b.y, w4b.z, w4b.w};
      #pragma unroll
      for (int n2=0;n2<4;n2++)
        #pragma unroll
        for (int mm=0;mm<8;mm++)
          acc[n2][mm] = fmaf(av[n2], wv[mm], acc[n2][mm]);
    }
    __syncthreads();
  }
  #pragma unroll
  for (int mm=0;mm<8;mm++){
    float bb = b1[8*tm+mm];
    #pragma unroll
    for (int n2=0;n2<4;n2++){
      h1T[8*tm+mm][4*tn+n2] = fmaxf(acc[n2][mm] + bb, 0.f);
      acc[n2][mm] = 0.f;
    }
  }
  __syncthreads();

  // layer 2: K = 256
  for (int kt = 0; kt < DMM; kt += 16){
    for (int i = t; i < 16*DMM; i += 256){
      int kk = i >> 8, m = i & (DMM-1);
      wT[kk][m] = W2T[(kt+kk)*DMM + m];
    }
    __syncthreads();
    #pragma unroll
    for (int kk=0; kk<16; kk++){
      float4 a4  = *(const float4*)&h1T[kt+kk][4*tn];
      float4 w4a = *(const float4*)&wT[kk][8*tm];
      float4 w4b = *(const float4*)&wT[kk][8*tm+4];
      float av[4] = {a4.x, a4.y, a4.z, a4.w};
      float wv[8] = {w4a.x, w4a.y, w4a.z, w4a.w, w4b.x, w4b.y, w4b.z, w4b.w};
      #pragma unroll
      for (int n2=0;n2<4;n2++)
        #pragma unroll
        for (int mm=0;mm<8;mm++)
          acc[n2][mm] = fmaf(av[n2], wv[mm], acc[n2][mm]);
    }
    __syncthreads();
  }

  // layer 3 + block reduce over the 32 tm groups
  float part[4] = {0.f,0.f,0.f,0.f};
  #pragma unroll
  for (int mm=0;mm<8;mm++){
    float w3 = W3[8*tm+mm];
    float bb = b2[8*tm+mm];
    #pragma unroll
    for (int n2=0;n2<4;n2++)
      part[n2] = fmaf(w3, fmaxf(acc[n2][mm] + bb, 0.f), part[n2]);
  }
  #pragma unroll
  for (int n2=0;n2<4;n2++) red[4*tn+n2][tm] = part[n2];
  __syncthreads();
  if (t < MTM){
    float s = 0.f;
    #pragma unroll
    for (int j=0;j<32;j++) s += red[t][j];
    int v = base + t;
    if (v < NN) out[v] = s + b3[0];
  }
}

extern "C" void kernel_launch(void* const* d_in, const int* in_sizes, int n_in,
                              void* d_out, int out_size, void* d_ws, size_t ws_size,
                              hipStream_t stream){
  if (ws_size < (size_t)WS_NEEDED) return;  // fail validation cleanly, don't fault
  const float* x      = (const float*)d_in[0];
  const int*   ei     = (const int*)  d_in[1];
  const int*   srcp   = ei;
  const int*   dstp   = ei + NE;
  const int*   fl     = (const int*)  d_in[2];
  const float* W_emd  = (const float*)d_in[3];
  const float* b_emd  = (const float*)d_in[4];
  const float* W_aggr = (const float*)d_in[5];
  const float* b_aggr = (const float*)d_in[6];
  const float* w_ih   = (const float*)d_in[7];
  const float* w_hh   = (const float*)d_in[8];
  const float* b_ih   = (const float*)d_in[9];
  const float* b_hh   = (const float*)d_in[10];
  const float* W1     = (const float*)d_in[11];
  const float* b1     = (const float*)d_in[12];
  const float* W2     = (const float*)d_in[13];
  const float* b2     = (const float*)d_in[14];
  const float* W3     = (const float*)d_in[15];
  const float* b3     = (const float*)d_in[16];

  char* ws = (char*)d_ws;
  float* h        = (float*)(ws + OFF_H);
  float* s_c      = (float*)(ws + OFF_SC);
  float* deg_c    = (float*)(ws + OFF_DEG);
  int*   node_list= (int*)  (ws + OFF_NLIST);
  int*   node_pos = (int*)  (ws + OFF_NPOS);
  int*   edge_list= (int*)  (ws + OFF_ELIST);
  float* WcT      = (float*)(ws + OFF_WCT);
  float* whhT     = (float*)(ws + OFF_WHHT);
  float* mb       = (float*)(ws + OFF_MB);
  float* W1T      = (float*)(ws + OFF_W1T);
  float* W2T      = (float*)(ws + OFF_W2T);
  int*   cnt      = (int*)  (ws + OFF_CNT);
  float* outp     = (float*)d_out;

  k_zero_cnt<<<1, 128, 0, stream>>>(cnt);
  k_init_h<<<4096, 256, 0, stream>>>(h, W_emd, b_emd);
  k_count<<<3125, 256, 0, stream>>>(fl, dstp, cnt);
  k_scan<<<1, 64, 0, stream>>>(cnt);
  k_fill<<<3125, 256, 0, stream>>>(fl, dstp, cnt, node_list, node_pos, edge_list);
  k_prep<<<256, 256, 0, stream>>>(w_ih, W_aggr, b_aggr, w_hh, W1, W2,
                                  WcT, whhT, mb, W1T, W2T);
  for (int l = 1; l < NLVL; l++){
    k_zero_s<<<1024, 256, 0, stream>>>(cnt, l, s_c, deg_c);
    k_scatter<<<2048, 256, 0, stream>>>(cnt, l, edge_list, srcp, dstp, node_pos,
                                        h, s_c, deg_c);
    k_gru<<<1024, 256, 0, stream>>>(cnt, l, node_list, s_c, deg_c, x,
                                    WcT, whhT, mb, w_ih, b_ih, b_hh, h);
  }
  k_mlp<<<(NN + MTM - 1)/MTM, 256, 0, stream>>>(h, W1T, b1, W2T, b2, W3, b3, outp);
}

// Round 3
// 2118.441 us; speedup vs baseline: 2.4874x; 2.4874x over previous
//
#include <hip/hip_runtime.h>

#define NN 200000
#define NE 600000
#define DD 128
#define DXX 3
#define DMM 256
#define NLVL 16
#define MAXLVL 16384   // max nodes per level (true ~12500, Binomial(200k,1/16))

// ---- workspace byte offsets (total ~115.6 MB) ----
#define OFF_H      0LL                      // float h[NN][128]         102,400,000
#define OFF_SC     102400000LL              // float s_c[MAXLVL][128]     8,388,608
#define OFF_DEG    110788608LL              // float deg_c[MAXLVL]           65,536
#define OFF_NLIST  110854144LL              // int node_list[NN]            800,000
#define OFF_NPOS   111654144LL              // int node_pos[NN]             800,000
#define OFF_ELIST  112454144LL              // int edge_list[NE]          2,400,000
#define OFF_WCT    114854144LL              // float WcT[128][384]          196,608
#define OFF_WHHT   115050752LL              // float whhT[128][384]         196,608
#define OFF_MB     115247360LL              // float mb[384]                  1,536
#define OFF_W1T    115248896LL              // float W1T[128][256]          131,072
#define OFF_W2T    115379968LL              // float W2T[256][256]          262,144
#define OFF_CNT    115642112LL              // int counters[128]                512
#define WS_NEEDED  115642624LL

// counter layout: [0..15] node_cnt  [16..31] edge_cnt
//                 [32..48] node_start(17)  [49..65] edge_start(17)
//                 [66..81] node_cur  [82..97] edge_cur

__device__ __forceinline__ float sigm(float x){
  x = fminf(fmaxf(x, -30.f), 30.f);
  return 1.f/(1.f + __expf(-x));
}
__device__ __forceinline__ float tanh_(float x){
  x = fminf(fmaxf(x, -15.f), 15.f);
  float e = __expf(2.f*x);
  return (e - 1.f)/(e + 1.f);
}

__global__ void k_zero_cnt(int* cnt){
  if (threadIdx.x < 128) cnt[threadIdx.x] = 0;
}

// h[v][d] = W_emd[d] + b_emd[d] for all v
__global__ void k_init_h(float* h, const float* W_emd, const float* b_emd){
  __shared__ float h0[DD];
  if (threadIdx.x < DD) h0[threadIdx.x] = W_emd[threadIdx.x] + b_emd[threadIdx.x];
  __syncthreads();
  const int tot = NN*DD/4;
  for (int i = blockIdx.x*blockDim.x + threadIdx.x; i < tot; i += gridDim.x*blockDim.x){
    int d0 = (i & 31)*4;
    ((float4*)h)[i] = make_float4(h0[d0], h0[d0+1], h0[d0+2], h0[d0+3]);
  }
}

// histogram nodes by level, edges by dst level
__global__ void k_count(const int* fl, const int* dst, int* cnt){
  __shared__ int hn[NLVL], he[NLVL];
  if (threadIdx.x < NLVL){ hn[threadIdx.x]=0; he[threadIdx.x]=0; }
  __syncthreads();
  const int tot = NN + NE;
  for (int i = blockIdx.x*blockDim.x + threadIdx.x; i < tot; i += gridDim.x*blockDim.x){
    if (i < NN) atomicAdd(&hn[fl[i]], 1);
    else        atomicAdd(&he[fl[dst[i-NN]]], 1);
  }
  __syncthreads();
  if (threadIdx.x < NLVL){
    if (hn[threadIdx.x]) atomicAdd(&cnt[threadIdx.x], hn[threadIdx.x]);
    if (he[threadIdx.x]) atomicAdd(&cnt[16+threadIdx.x], he[threadIdx.x]);
  }
}

__global__ void k_scan(int* cnt){
  if (threadIdx.x == 0){
    int s = 0;
    for (int l=0;l<NLVL;l++){ cnt[32+l] = s; s += cnt[l]; }
    cnt[48] = s;
    s = 0;
    for (int l=0;l<NLVL;l++){ cnt[49+l] = s; s += cnt[16+l]; }
    cnt[65] = s;
    for (int l=0;l<NLVL;l++){ cnt[66+l]=0; cnt[82+l]=0; }
  }
}

// ---- counting-sort fill, 3-phase per 1024-item tile:
//  (1) LDS-atomic histogram, record local rank
//  (2) ONE global atomicAdd per (tile, level) to reserve a chunk
//  (3) write at start[l] + chunk_base[l] + rank
// replaces per-element global atomics on 16 hot counters (was ~3 ms).
#define FB 1024
__global__ __launch_bounds__(256) void k_fill_n(const int* fl, int* cnt,
                                                int* node_list, int* node_pos){
  __shared__ int hist[NLVL], base[NLVL];
  const int nt = (NN + FB - 1)/FB;
  for (int tile = blockIdx.x; tile < nt; tile += gridDim.x){
    const int i0 = tile*FB;
    if (threadIdx.x < NLVL) hist[threadIdx.x] = 0;
    __syncthreads();
    int lv[4], rk[4];
    #pragma unroll
    for (int j=0;j<4;j++){
      int i = i0 + threadIdx.x + j*256;
      if (i < NN){
        int l = fl[i];
        lv[j] = l;
        rk[j] = atomicAdd(&hist[l], 1);
      } else lv[j] = -1;
    }
    __syncthreads();
    if (threadIdx.x < NLVL)
      base[threadIdx.x] = atomicAdd(&cnt[66+threadIdx.x], hist[threadIdx.x]);
    __syncthreads();
    #pragma unroll
    for (int j=0;j<4;j++){
      if (lv[j] >= 0){
        int i = i0 + threadIdx.x + j*256;
        int p = base[lv[j]] + rk[j];
        node_list[cnt[32+lv[j]] + p] = i;
        node_pos[i] = (p < MAXLVL) ? p : (MAXLVL-1);  // clamp: OOB-safe
      }
    }
    __syncthreads();
  }
}

__global__ __launch_bounds__(256) void k_fill_e(const int* fl, const int* dst,
                                                int* cnt, int* edge_list){
  __shared__ int hist[NLVL], base[NLVL];
  const int nt = (NE + FB - 1)/FB;
  for (int tile = blockIdx.x; tile < nt; tile += gridDim.x){
    const int i0 = tile*FB;
    if (threadIdx.x < NLVL) hist[threadIdx.x] = 0;
    __syncthreads();
    int lv[4], rk[4];
    #pragma unroll
    for (int j=0;j<4;j++){
      int e = i0 + threadIdx.x + j*256;
      if (e < NE){
        int l = fl[dst[e]];
        lv[j] = l;
        rk[j] = atomicAdd(&hist[l], 1);
      } else lv[j] = -1;
    }
    __syncthreads();
    if (threadIdx.x < NLVL)
      base[threadIdx.x] = atomicAdd(&cnt[82+threadIdx.x], hist[threadIdx.x]);
    __syncthreads();
    #pragma unroll
    for (int j=0;j<4;j++){
      if (lv[j] >= 0){
        int e = i0 + threadIdx.x + j*256;
        edge_list[cnt[49+lv[j]] + base[lv[j]] + rk[j]] = e;
      }
    }
    __syncthreads();
  }
}

// Precompute WcT[k][r] = sum_j w_ih[r][j]*W_aggr[j][k]; whhT; mb; W1T; W2T
__global__ void k_prep(const float* w_ih, const float* W_aggr, const float* b_aggr,
                       const float* w_hh, const float* W1, const float* W2,
                       float* WcT, float* whhT, float* mb, float* W1T, float* W2T){
  const int tid = blockIdx.x*blockDim.x + threadIdx.x;
  const int stride = gridDim.x*blockDim.x;
  for (int i = tid; i < 384*DD; i += stride){
    int r = i >> 7, k = i & (DD-1);
    float s = 0.f;
    for (int j=0;j<DD;j++) s += w_ih[r*(DD+DXX)+j]*W_aggr[j*DD+k];
    WcT[k*384 + r] = s;
  }
  for (int i = tid; i < 384*DD; i += stride){
    int r = i >> 7, k = i & (DD-1);
    whhT[k*384 + r] = w_hh[r*DD + k];
  }
  for (int i = tid; i < 384; i += stride){
    float s = 0.f;
    for (int j=0;j<DD;j++) s += w_ih[i*(DD+DXX)+j]*b_aggr[j];
    mb[i] = s;
  }
  for (int i = tid; i < DD*DMM; i += stride){
    int m = i & (DMM-1), k = i >> 8;
    W1T[k*DMM + m] = W1[m*DD + k];
  }
  for (int i = tid; i < DMM*DMM; i += stride){
    int m = i & (DMM-1), k = i >> 8;
    W2T[k*DMM + m] = W2[m*DMM + k];
  }
}

__global__ void k_zero_s(const int* cnt, int l, float* s_c, float* deg_c){
  int na = cnt[32+l+1] - cnt[32+l];
  if (na > MAXLVL) na = MAXLVL;
  const int tot = na*DD;
  const int stride = gridDim.x*blockDim.x;
  for (int i = blockIdx.x*blockDim.x + threadIdx.x; i < tot; i += stride) s_c[i] = 0.f;
  for (int i = blockIdx.x*blockDim.x + threadIdx.x; i < na;  i += stride) deg_c[i] = 0.f;
}

// scatter-add h[src] into compact s_c rows (dst nodes of this level)
__global__ void k_scatter(const int* cnt, int l, const int* edge_list,
                          const int* srcp, const int* dstp, const int* node_pos,
                          const float* h, float* s_c, float* deg_c){
  const int e0 = cnt[49+l];
  const int ne = cnt[49+l+1] - e0;
  const int tot = ne*DD;
  const int stride = gridDim.x*blockDim.x;
  for (int i = blockIdx.x*blockDim.x + threadIdx.x; i < tot; i += stride){
    int ei = i >> 7, d = i & (DD-1);
    int e  = edge_list[e0 + ei];
    int sv = srcp[e], dv = dstp[e];
    atomicAdd(&s_c[node_pos[dv]*DD + d], h[sv*DD + d]);
    if (d == 0) atomicAdd(&deg_c[node_pos[dv]], 1.f);
  }
}

// GRU update for the level's nodes. 32 nodes/block, 256 threads.
// thread t: j = t&127 (hidden index), g = t>>7 handles nodes {2n+g}.
#define GTM 32
__global__ __launch_bounds__(256) void k_gru(const int* cnt, int l,
    const int* node_list, const float* s_c, const float* deg_c,
    const float* x, const float* WcT, const float* whhT, const float* mb,
    const float* w_ih, const float* b_ih, const float* b_hh, float* h){
  const int n0 = cnt[32+l];
  int na = cnt[32+l+1] - n0;
  if (na > MAXLVL) na = MAXLVL;
  if (na <= 0) return;
  const int ntiles = (na + GTM-1)/GTM;
  __shared__ float s_l[GTM][DD];
  __shared__ float h_l[GTM][DD];
  __shared__ float x_l[GTM][4];
  __shared__ float deg_l[GTM];
  __shared__ int   vidx[GTM];
  const int t  = threadIdx.x;
  const int jt = t & (DD-1);
  const int g  = t >> 7;
  for (int tile = blockIdx.x; tile < ntiles; tile += gridDim.x){
    const int tb = tile*GTM;
    if (t < GTM){
      int v = (tb + t < na) ? node_list[n0 + tb + t] : -1;
      vidx[t] = v;
      deg_l[t] = (tb + t < na) ? deg_c[tb + t] : 0.f;
      for (int kx=0; kx<DXX; kx++) x_l[t][kx] = (v >= 0) ? x[v*DXX + kx] : 0.f;
    }
    for (int i = t; i < GTM*DD; i += 256){
      int j = i >> 7, k = i & (DD-1);
      int row = tb + j;
      float sv = 0.f, hv = 0.f;
      if (row < na){
        sv = s_c[row*DD + k];
        hv = h[node_list[n0 + row]*DD + k];
      }
      s_l[j][k] = sv;
      h_l[j][k] = hv;
    }
    __syncthreads();

    float agr[16], agz[16], agn[16], ahr[16], ahz[16], ahn[16];
    #pragma unroll
    for (int n=0;n<16;n++){ agr[n]=0.f; agz[n]=0.f; agn[n]=0.f; ahr[n]=0.f; ahz[n]=0.f; ahn[n]=0.f; }

    #pragma unroll 2
    for (int k=0;k<DD;k++){
      float w1 = WcT[k*384 + jt];
      float w2 = WcT[k*384 + 128 + jt];
      float w3 = WcT[k*384 + 256 + jt];
      float u1 = whhT[k*384 + jt];
      float u2 = whhT[k*384 + 128 + jt];
      float u3 = whhT[k*384 + 256 + jt];
      #pragma unroll
      for (int n=0;n<16;n++){
        int node = 2*n + g;
        float sv = s_l[node][k];
        float hv = h_l[node][k];
        agr[n] = fmaf(w1, sv, agr[n]);
        agz[n] = fmaf(w2, sv, agz[n]);
        agn[n] = fmaf(w3, sv, agn[n]);
        ahr[n] = fmaf(u1, hv, ahr[n]);
        ahz[n] = fmaf(u2, hv, ahz[n]);
        ahn[n] = fmaf(u3, hv, ahn[n]);
      }
    }
    // x part (feeds gi only)
    #pragma unroll
    for (int kx=0;kx<DXX;kx++){
      float wx1 = w_ih[jt*(DD+DXX) + DD + kx];
      float wx2 = w_ih[(128+jt)*(DD+DXX) + DD + kx];
      float wx3 = w_ih[(256+jt)*(DD+DXX) + DD + kx];
      #pragma unroll
      for (int n=0;n<16;n++){
        int node = 2*n + g;
        float xv = x_l[node][kx];
        agr[n] = fmaf(wx1, xv, agr[n]);
        agz[n] = fmaf(wx2, xv, agz[n]);
        agn[n] = fmaf(wx3, xv, agn[n]);
      }
    }
    float bi1 = b_ih[jt], bi2 = b_ih[128+jt], bi3 = b_ih[256+jt];
    float bh1 = b_hh[jt], bh2 = b_hh[128+jt], bh3 = b_hh[256+jt];
    float m1 = mb[jt], m2 = mb[128+jt], m3 = mb[256+jt];
    #pragma unroll
    for (int n=0;n<16;n++){
      int node = 2*n + g;
      int v = vidx[node];
      if (v < 0) continue;
      float dg = deg_l[node];
      float gr = agr[n] + bi1 + dg*m1 + ahr[n] + bh1;
      float gz = agz[n] + bi2 + dg*m2 + ahz[n] + bh2;
      float rr = sigm(gr);
      float zz = sigm(gz);
      float gn = agn[n] + bi3 + dg*m3 + rr*(ahn[n] + bh3);
      float nv = tanh_(gn);
      float hv = h_l[node][jt];
      h[v*DD + jt] = (1.f - zz)*nv + zz*hv;
    }
    __syncthreads();
  }
}

// fused MLP: h(128) -> relu 256 -> relu 256 -> 1. 32 nodes/block, 256 threads,
// register tile 4 nodes x 8 outputs. Weights staged to LDS in 16-row K tiles.
#define MTM 32
#define HTP 36
__global__ __launch_bounds__(256) void k_mlp(const float* h,
    const float* W1T, const float* b1, const float* W2T, const float* b2,
    const float* W3, const float* b3, float* out){
  __shared__ __align__(16) float hT[DD][HTP];    // 18.4 KB  (hT[k][n])
  __shared__ __align__(16) float h1T[DMM][HTP];  // 36.9 KB  (h1T[m][n])
  __shared__ __align__(16) float wT[16][DMM];    // 16.4 KB
  __shared__ float red[MTM][33];                 // 4.2 KB
  const int t  = threadIdx.x;
  const int tn = t & 7;    // 4 nodes: 4*tn..4*tn+3
  const int tm = t >> 3;   // 8 outputs: 8*tm..8*tm+7
  const int base = blockIdx.x*MTM;

  for (int i = t; i < MTM*DD; i += 256){
    int n = i >> 7, k = i & (DD-1);
    int v = base + n;
    hT[k][n] = (v < NN) ? h[v*DD + k] : 0.f;
  }
  __syncthreads();

  float acc[4][8];
  #pragma unroll
  for (int a=0;a<4;a++)
    #pragma unroll
    for (int b=0;b<8;b++) acc[a][b] = 0.f;

  // layer 1: K = 128
  for (int kt = 0; kt < DD; kt += 16){
    for (int i = t; i < 16*DMM; i += 256){
      int kk = i >> 8, m = i & (DMM-1);
      wT[kk][m] = W1T[(kt+kk)*DMM + m];
    }
    __syncthreads();
    #pragma unroll
    for (int kk=0; kk<16; kk++){
      float4 a4  = *(const float4*)&hT[kt+kk][4*tn];
      float4 w4a = *(const float4*)&wT[kk][8*tm];
      float4 w4b = *(const float4*)&wT[kk][8*tm+4];
      float av[4] = {a4.x, a4.y, a4.z, a4.w};
      float wv[8] = {w4a.x, w4a.y, w4a.z, w4a.w, w4b.x, w4b.y, w4b.z, w4b.w};
      #pragma unroll
      for (int n2=0;n2<4;n2++)
        #pragma unroll
        for (int mm=0;mm<8;mm++)
          acc[n2][mm] = fmaf(av[n2], wv[mm], acc[n2][mm]);
    }
    __syncthreads();
  }
  #pragma unroll
  for (int mm=0;mm<8;mm++){
    float bb = b1[8*tm+mm];
    #pragma unroll
    for (int n2=0;n2<4;n2++){
      h1T[8*tm+mm][4*tn+n2] = fmaxf(acc[n2][mm] + bb, 0.f);
      acc[n2][mm] = 0.f;
    }
  }
  __syncthreads();

  // layer 2: K = 256
  for (int kt = 0; kt < DMM; kt += 16){
    for (int i = t; i < 16*DMM; i += 256){
      int kk = i >> 8, m = i & (DMM-1);
      wT[kk][m] = W2T[(kt+kk)*DMM + m];
    }
    __syncthreads();
    #pragma unroll
    for (int kk=0; kk<16; kk++){
      float4 a4  = *(const float4*)&h1T[kt+kk][4*tn];
      float4 w4a = *(const float4*)&wT[kk][8*tm];
      float4 w4b = *(const float4*)&wT[kk][8*tm+4];
      float av[4] = {a4.x, a4.y, a4.z, a4.w};
      float wv[8] = {w4a.x, w4a.y, w4a.z, w4a.w, w4b.x, w4b.y, w4b.z, w4b.w};
      #pragma unroll
      for (int n2=0;n2<4;n2++)
        #pragma unroll
        for (int mm=0;mm<8;mm++)
          acc[n2][mm] = fmaf(av[n2], wv[mm], acc[n2][mm]);
    }
    __syncthreads();
  }

  // layer 3 + block reduce over the 32 tm groups
  float part[4] = {0.f,0.f,0.f,0.f};
  #pragma unroll
  for (int mm=0;mm<8;mm++){
    float w3 = W3[8*tm+mm];
    float bb = b2[8*tm+mm];
    #pragma unroll
    for (int n2=0;n2<4;n2++)
      part[n2] = fmaf(w3, fmaxf(acc[n2][mm] + bb, 0.f), part[n2]);
  }
  #pragma unroll
  for (int n2=0;n2<4;n2++) red[4*tn+n2][tm] = part[n2];
  __syncthreads();
  if (t < MTM){
    float s = 0.f;
    #pragma unroll
    for (int j=0;j<32;j++) s += red[t][j];
    int v = base + t;
    if (v < NN) out[v] = s + b3[0];
  }
}

extern "C" void kernel_launch(void* const* d_in, const int* in_sizes, int n_in,
                              void* d_out, int out_size, void* d_ws, size_t ws_size,
                              hipStream_t stream){
  if (ws_size < (size_t)WS_NEEDED) return;  // fail validation cleanly, don't fault
  const float* x      = (const float*)d_in[0];
  const int*   ei     = (const int*)  d_in[1];
  const int*   srcp   = ei;
  const int*   dstp   = ei + NE;
  const int*   fl     = (const int*)  d_in[2];
  const float* W_emd  = (const float*)d_in[3];
  const float* b_emd  = (const float*)d_in[4];
  const float* W_aggr = (const float*)d_in[5];
  const float* b_aggr = (const float*)d_in[6];
  const float* w_ih   = (const float*)d_in[7];
  const float* w_hh   = (const float*)d_in[8];
  const float* b_ih   = (const float*)d_in[9];
  const float* b_hh   = (const float*)d_in[10];
  const float* W1     = (const float*)d_in[11];
  const float* b1     = (const float*)d_in[12];
  const float* W2     = (const float*)d_in[13];
  const float* b2     = (const float*)d_in[14];
  const float* W3     = (const float*)d_in[15];
  const float* b3     = (const float*)d_in[16];

  char* ws = (char*)d_ws;
  float* h        = (float*)(ws + OFF_H);
  float* s_c      = (float*)(ws + OFF_SC);
  float* deg_c    = (float*)(ws + OFF_DEG);
  int*   node_list= (int*)  (ws + OFF_NLIST);
  int*   node_pos = (int*)  (ws + OFF_NPOS);
  int*   edge_list= (int*)  (ws + OFF_ELIST);
  float* WcT      = (float*)(ws + OFF_WCT);
  float* whhT     = (float*)(ws + OFF_WHHT);
  float* mb       = (float*)(ws + OFF_MB);
  float* W1T      = (float*)(ws + OFF_W1T);
  float* W2T      = (float*)(ws + OFF_W2T);
  int*   cnt      = (int*)  (ws + OFF_CNT);
  float* outp     = (float*)d_out;

  k_zero_cnt<<<1, 128, 0, stream>>>(cnt);
  k_init_h<<<4096, 256, 0, stream>>>(h, W_emd, b_emd);
  k_count<<<3125, 256, 0, stream>>>(fl, dstp, cnt);
  k_scan<<<1, 64, 0, stream>>>(cnt);
  k_fill_n<<<196, 256, 0, stream>>>(fl, cnt, node_list, node_pos);
  k_fill_e<<<586, 256, 0, stream>>>(fl, dstp, cnt, edge_list);
  k_prep<<<256, 256, 0, stream>>>(w_ih, W_aggr, b_aggr, w_hh, W1, W2,
                                  WcT, whhT, mb, W1T, W2T);
  for (int l = 1; l < NLVL; l++){
    k_zero_s<<<1024, 256, 0, stream>>>(cnt, l, s_c, deg_c);
    k_scatter<<<2048, 256, 0, stream>>>(cnt, l, edge_list, srcp, dstp, node_pos,
                                        h, s_c, deg_c);
    k_gru<<<1024, 256, 0, stream>>>(cnt, l, node_list, s_c, deg_c, x,
                                    WcT, whhT, mb, w_ih, b_ih, b_hh, h);
  }
  k_mlp<<<(NN + MTM - 1)/MTM, 256, 0, stream>>>(h, W1T, b1, W2T, b2, W3, b3, outp);
}

// Round 4
// 1744.305 us; speedup vs baseline: 3.0210x; 1.2145x over previous
//
#include <hip/hip_runtime.h>

#define NN 200000
#define NE 600000
#define DD 128
#define DXX 3
#define DMM 256
#define NLVL 16
#define MAXLVL 16384   // max nodes per level (true ~12500, Binomial(200k,1/16))

// ---- workspace byte offsets (total ~115.6 MB) ----
#define OFF_H      0LL                      // float h[NN][128]         102,400,000
#define OFF_SC     102400000LL              // float s_c[MAXLVL][128]     8,388,608
#define OFF_DEG    110788608LL              // float deg_c[MAXLVL]           65,536
#define OFF_NLIST  110854144LL              // int node_list[NN]            800,000
#define OFF_NPOS   111654144LL              // int node_pos[NN]             800,000
#define OFF_ELIST  112454144LL              // int edge_list[NE]          2,400,000
#define OFF_WCT    114854144LL              // float WcT[128][384]          196,608
#define OFF_WHHT   115050752LL              // float whhT[128][384]         196,608
#define OFF_MB     115247360LL              // float mb[384]                  1,536
#define OFF_W1H    115248896LL              // _Float16 W1h[256][128]        65,536 (in old W1T slot)
#define OFF_W2H    115379968LL              // _Float16 W2h[256][256]       131,072 (in old W2T slot)
#define OFF_CNT    115642112LL              // int counters[128]                512
#define WS_NEEDED  115642624LL

typedef float    f32x4 __attribute__((ext_vector_type(4)));
typedef _Float16 f16x8 __attribute__((ext_vector_type(8)));
typedef _Float16 f16x4 __attribute__((ext_vector_type(4)));

__device__ __forceinline__ float sigm(float x){
  x = fminf(fmaxf(x, -30.f), 30.f);
  return 1.f/(1.f + __expf(-x));
}
__device__ __forceinline__ float tanh_(float x){
  x = fminf(fmaxf(x, -15.f), 15.f);
  float e = __expf(2.f*x);
  return (e - 1.f)/(e + 1.f);
}

__global__ void k_zero_cnt(int* cnt){
  if (threadIdx.x < 128) cnt[threadIdx.x] = 0;
}

// h[v][d] = W_emd[d] + b_emd[d] for all v
__global__ void k_init_h(float* h, const float* W_emd, const float* b_emd){
  __shared__ float h0[DD];
  if (threadIdx.x < DD) h0[threadIdx.x] = W_emd[threadIdx.x] + b_emd[threadIdx.x];
  __syncthreads();
  const int tot = NN*DD/4;
  for (int i = blockIdx.x*blockDim.x + threadIdx.x; i < tot; i += gridDim.x*blockDim.x){
    int d0 = (i & 31)*4;
    ((float4*)h)[i] = make_float4(h0[d0], h0[d0+1], h0[d0+2], h0[d0+3]);
  }
}

// histogram nodes by level, edges by dst level
__global__ void k_count(const int* fl, const int* dst, int* cnt){
  __shared__ int hn[NLVL], he[NLVL];
  if (threadIdx.x < NLVL){ hn[threadIdx.x]=0; he[threadIdx.x]=0; }
  __syncthreads();
  const int tot = NN + NE;
  for (int i = blockIdx.x*blockDim.x + threadIdx.x; i < tot; i += gridDim.x*blockDim.x){
    if (i < NN) atomicAdd(&hn[fl[i]], 1);
    else        atomicAdd(&he[fl[dst[i-NN]]], 1);
  }
  __syncthreads();
  if (threadIdx.x < NLVL){
    if (hn[threadIdx.x]) atomicAdd(&cnt[threadIdx.x], hn[threadIdx.x]);
    if (he[threadIdx.x]) atomicAdd(&cnt[16+threadIdx.x], he[threadIdx.x]);
  }
}

__global__ void k_scan(int* cnt){
  if (threadIdx.x == 0){
    int s = 0;
    for (int l=0;l<NLVL;l++){ cnt[32+l] = s; s += cnt[l]; }
    cnt[48] = s;
    s = 0;
    for (int l=0;l<NLVL;l++){ cnt[49+l] = s; s += cnt[16+l]; }
    cnt[65] = s;
    for (int l=0;l<NLVL;l++){ cnt[66+l]=0; cnt[82+l]=0; }
  }
}

// ---- counting-sort fill: LDS histogram + one global atomic per (tile,level)
#define FB 1024
__global__ __launch_bounds__(256) void k_fill_n(const int* fl, int* cnt,
                                                int* node_list, int* node_pos){
  __shared__ int hist[NLVL], base[NLVL];
  const int nt = (NN + FB - 1)/FB;
  for (int tile = blockIdx.x; tile < nt; tile += gridDim.x){
    const int i0 = tile*FB;
    if (threadIdx.x < NLVL) hist[threadIdx.x] = 0;
    __syncthreads();
    int lv[4], rk[4];
    #pragma unroll
    for (int j=0;j<4;j++){
      int i = i0 + threadIdx.x + j*256;
      if (i < NN){
        int l = fl[i];
        lv[j] = l;
        rk[j] = atomicAdd(&hist[l], 1);
      } else lv[j] = -1;
    }
    __syncthreads();
    if (threadIdx.x < NLVL)
      base[threadIdx.x] = atomicAdd(&cnt[66+threadIdx.x], hist[threadIdx.x]);
    __syncthreads();
    #pragma unroll
    for (int j=0;j<4;j++){
      if (lv[j] >= 0){
        int i = i0 + threadIdx.x + j*256;
        int p = base[lv[j]] + rk[j];
        node_list[cnt[32+lv[j]] + p] = i;
        node_pos[i] = (p < MAXLVL) ? p : (MAXLVL-1);  // clamp: OOB-safe
      }
    }
    __syncthreads();
  }
}

__global__ __launch_bounds__(256) void k_fill_e(const int* fl, const int* dst,
                                                int* cnt, int* edge_list){
  __shared__ int hist[NLVL], base[NLVL];
  const int nt = (NE + FB - 1)/FB;
  for (int tile = blockIdx.x; tile < nt; tile += gridDim.x){
    const int i0 = tile*FB;
    if (threadIdx.x < NLVL) hist[threadIdx.x] = 0;
    __syncthreads();
    int lv[4], rk[4];
    #pragma unroll
    for (int j=0;j<4;j++){
      int e = i0 + threadIdx.x + j*256;
      if (e < NE){
        int l = fl[dst[e]];
        lv[j] = l;
        rk[j] = atomicAdd(&hist[l], 1);
      } else lv[j] = -1;
    }
    __syncthreads();
    if (threadIdx.x < NLVL)
      base[threadIdx.x] = atomicAdd(&cnt[82+threadIdx.x], hist[threadIdx.x]);
    __syncthreads();
    #pragma unroll
    for (int j=0;j<4;j++){
      if (lv[j] >= 0){
        int e = i0 + threadIdx.x + j*256;
        edge_list[cnt[49+lv[j]] + base[lv[j]] + rk[j]] = e;
      }
    }
    __syncthreads();
  }
}

// Precompute WcT[k][r] = sum_j w_ih[r][j]*W_aggr[j][k]; whhT; mb; fp16 W1/W2
__global__ void k_prep(const float* w_ih, const float* W_aggr, const float* b_aggr,
                       const float* w_hh, const float* W1, const float* W2,
                       float* WcT, float* whhT, float* mb, _Float16* W1h, _Float16* W2h){
  const int tid = blockIdx.x*blockDim.x + threadIdx.x;
  const int stride = gridDim.x*blockDim.x;
  for (int i = tid; i < 384*DD; i += stride){
    int r = i >> 7, k = i & (DD-1);
    float s = 0.f;
    for (int j=0;j<DD;j++) s += w_ih[r*(DD+DXX)+j]*W_aggr[j*DD+k];
    WcT[k*384 + r] = s;
  }
  for (int i = tid; i < 384*DD; i += stride){
    int r = i >> 7, k = i & (DD-1);
    whhT[k*384 + r] = w_hh[r*DD + k];
  }
  for (int i = tid; i < 384; i += stride){
    float s = 0.f;
    for (int j=0;j<DD;j++) s += w_ih[i*(DD+DXX)+j]*b_aggr[j];
    mb[i] = s;
  }
  for (int i = tid; i < DMM*DD;  i += stride) W1h[i] = (_Float16)W1[i];
  for (int i = tid; i < DMM*DMM; i += stride) W2h[i] = (_Float16)W2[i];
}

__global__ void k_zero_s(const int* cnt, int l, float* s_c, float* deg_c){
  int na = cnt[32+l+1] - cnt[32+l];
  if (na > MAXLVL) na = MAXLVL;
  const int tot = na*DD;
  const int stride = gridDim.x*blockDim.x;
  for (int i = blockIdx.x*blockDim.x + threadIdx.x; i < tot; i += stride) s_c[i] = 0.f;
  for (int i = blockIdx.x*blockDim.x + threadIdx.x; i < na;  i += stride) deg_c[i] = 0.f;
}

// scatter-add h[src] into compact s_c rows (dst nodes of this level)
__global__ void k_scatter(const int* cnt, int l, const int* edge_list,
                          const int* srcp, const int* dstp, const int* node_pos,
                          const float* h, float* s_c, float* deg_c){
  const int e0 = cnt[49+l];
  const int ne = cnt[49+l+1] - e0;
  const int tot = ne*DD;
  const int stride = gridDim.x*blockDim.x;
  for (int i = blockIdx.x*blockDim.x + threadIdx.x; i < tot; i += stride){
    int ei = i >> 7, d = i & (DD-1);
    int e  = edge_list[e0 + ei];
    int sv = srcp[e], dv = dstp[e];
    atomicAdd(&s_c[node_pos[dv]*DD + d], h[sv*DD + d]);
    if (d == 0) atomicAdd(&deg_c[node_pos[dv]], 1.f);
  }
}

// GRU update for the level's nodes. 32 nodes/block, 256 threads.
#define GTM 32
__global__ __launch_bounds__(256) void k_gru(const int* cnt, int l,
    const int* node_list, const float* s_c, const float* deg_c,
    const float* x, const float* WcT, const float* whhT, const float* mb,
    const float* w_ih, const float* b_ih, const float* b_hh, float* h){
  const int n0 = cnt[32+l];
  int na = cnt[32+l+1] - n0;
  if (na > MAXLVL) na = MAXLVL;
  if (na <= 0) return;
  const int ntiles = (na + GTM-1)/GTM;
  __shared__ float s_l[GTM][DD];
  __shared__ float h_l[GTM][DD];
  __shared__ float x_l[GTM][4];
  __shared__ float deg_l[GTM];
  __shared__ int   vidx[GTM];
  const int t  = threadIdx.x;
  const int jt = t & (DD-1);
  const int g  = t >> 7;
  for (int tile = blockIdx.x; tile < ntiles; tile += gridDim.x){
    const int tb = tile*GTM;
    if (t < GTM){
      int v = (tb + t < na) ? node_list[n0 + tb + t] : -1;
      vidx[t] = v;
      deg_l[t] = (tb + t < na) ? deg_c[tb + t] : 0.f;
      for (int kx=0; kx<DXX; kx++) x_l[t][kx] = (v >= 0) ? x[v*DXX + kx] : 0.f;
    }
    for (int i = t; i < GTM*DD; i += 256){
      int j = i >> 7, k = i & (DD-1);
      int row = tb + j;
      float sv = 0.f, hv = 0.f;
      if (row < na){
        sv = s_c[row*DD + k];
        hv = h[node_list[n0 + row]*DD + k];
      }
      s_l[j][k] = sv;
      h_l[j][k] = hv;
    }
    __syncthreads();

    float agr[16], agz[16], agn[16], ahr[16], ahz[16], ahn[16];
    #pragma unroll
    for (int n=0;n<16;n++){ agr[n]=0.f; agz[n]=0.f; agn[n]=0.f; ahr[n]=0.f; ahz[n]=0.f; ahn[n]=0.f; }

    #pragma unroll 2
    for (int k=0;k<DD;k++){
      float w1 = WcT[k*384 + jt];
      float w2 = WcT[k*384 + 128 + jt];
      float w3 = WcT[k*384 + 256 + jt];
      float u1 = whhT[k*384 + jt];
      float u2 = whhT[k*384 + 128 + jt];
      float u3 = whhT[k*384 + 256 + jt];
      #pragma unroll
      for (int n=0;n<16;n++){
        int node = 2*n + g;
        float sv = s_l[node][k];
        float hv = h_l[node][k];
        agr[n] = fmaf(w1, sv, agr[n]);
        agz[n] = fmaf(w2, sv, agz[n]);
        agn[n] = fmaf(w3, sv, agn[n]);
        ahr[n] = fmaf(u1, hv, ahr[n]);
        ahz[n] = fmaf(u2, hv, ahz[n]);
        ahn[n] = fmaf(u3, hv, ahn[n]);
      }
    }
    #pragma unroll
    for (int kx=0;kx<DXX;kx++){
      float wx1 = w_ih[jt*(DD+DXX) + DD + kx];
      float wx2 = w_ih[(128+jt)*(DD+DXX) + DD + kx];
      float wx3 = w_ih[(256+jt)*(DD+DXX) + DD + kx];
      #pragma unroll
      for (int n=0;n<16;n++){
        int node = 2*n + g;
        float xv = x_l[node][kx];
        agr[n] = fmaf(wx1, xv, agr[n]);
        agz[n] = fmaf(wx2, xv, agz[n]);
        agn[n] = fmaf(wx3, xv, agn[n]);
      }
    }
    float bi1 = b_ih[jt], bi2 = b_ih[128+jt], bi3 = b_ih[256+jt];
    float bh1 = b_hh[jt], bh2 = b_hh[128+jt], bh3 = b_hh[256+jt];
    float m1 = mb[jt], m2 = mb[128+jt], m3 = mb[256+jt];
    #pragma unroll
    for (int n=0;n<16;n++){
      int node = 2*n + g;
      int v = vidx[node];
      if (v < 0) continue;
      float dg = deg_l[node];
      float gr = agr[n] + bi1 + dg*m1 + ahr[n] + bh1;
      float gz = agz[n] + bi2 + dg*m2 + ahz[n] + bh2;
      float rr = sigm(gr);
      float zz = sigm(gz);
      float gn = agn[n] + bi3 + dg*m3 + rr*(ahn[n] + bh3);
      float nv = tanh_(gn);
      float hv = h_l[node][jt];
      h[v*DD + jt] = (1.f - zz)*nv + zz*hv;
    }
    __syncthreads();
  }
}

// MFMA MLP: h(128) -> relu 256 -> relu 256 -> 1.  64 nodes/block, 4 waves.
// Wave w owns m-rows 16w..16w+15 and all 256 outputs per layer.
// A-frags in regs; B-frags streamed from L2-resident fp16 weights.
// MFMA 16x16x32_f16 layouts: A/B lane l: row/col=l&15, k=8*(l>>4)+i;
// C/D lane l reg r: row=4*(l>>4)+r, col=l&15  [m89-verified, dtype-indep].
__global__ __launch_bounds__(256, 2) void k_mlp_mfma(const float* __restrict__ h,
    const _Float16* __restrict__ W1h, const float* __restrict__ b1,
    const _Float16* __restrict__ W2h, const float* __restrict__ b2,
    const float* __restrict__ W3, const float* __restrict__ b3,
    float* __restrict__ out){
  __shared__ _Float16 hA[64][136];    // 17.4 KB, pitch 136: 2-way-only conflicts
  __shared__ _Float16 h1s[64][264];   // 33.8 KB, pitch 264
  const int t    = threadIdx.x;
  const int lane = t & 63;
  const int w    = t >> 6;
  const int c    = lane & 15;
  const int g    = lane >> 4;
  const int base = blockIdx.x * 64;   // NN = 3125*64 exactly

  // stage h -> fp16 LDS (coalesced float4 reads)
  for (int q = t; q < 64*32; q += 256){
    int r = q >> 5, c4 = (q & 31)*4;
    float4 v = *(const float4*)(h + (size_t)(base + r)*DD + c4);
    f16x4 hv = { (_Float16)v.x, (_Float16)v.y, (_Float16)v.z, (_Float16)v.w };
    *(f16x4*)&hA[r][c4] = hv;
  }
  __syncthreads();

  f16x8 a1[4];
  #pragma unroll
  for (int s = 0; s < 4; s++)
    a1[s] = *(const f16x8*)&hA[w*16 + c][s*32 + 8*g];

  f32x4 acc[16];
  #pragma unroll
  for (int i = 0; i < 16; i++) acc[i] = (f32x4){0.f,0.f,0.f,0.f};

  // layer 1: K=128 (4 k-steps), 16 n-tiles
  #pragma unroll
  for (int tt = 0; tt < 16; tt++){
    const _Float16* wp = W1h + (tt*16 + c)*DD + 8*g;
    #pragma unroll
    for (int s = 0; s < 4; s++){
      f16x8 b = *(const f16x8*)(wp + s*32);
      acc[tt] = __builtin_amdgcn_mfma_f32_16x16x32_f16(a1[s], b, acc[tt], 0, 0, 0);
    }
  }

  // h1 = relu(acc + b1) -> LDS fp16
  #pragma unroll
  for (int tt = 0; tt < 16; tt++){
    float bb = b1[tt*16 + c];
    #pragma unroll
    for (int r = 0; r < 4; r++)
      h1s[w*16 + 4*g + r][tt*16 + c] = (_Float16)fmaxf(acc[tt][r] + bb, 0.f);
  }
  __syncthreads();

  f16x8 a2[8];
  #pragma unroll
  for (int s = 0; s < 8; s++)
    a2[s] = *(const f16x8*)&h1s[w*16 + c][s*32 + 8*g];

  #pragma unroll
  for (int i = 0; i < 16; i++) acc[i] = (f32x4){0.f,0.f,0.f,0.f};

  // layer 2: K=256 (8 k-steps), 16 n-tiles
  #pragma unroll
  for (int tt = 0; tt < 16; tt++){
    const _Float16* wp = W2h + (tt*16 + c)*DMM + 8*g;
    #pragma unroll
    for (int s = 0; s < 8; s++){
      f16x8 b = *(const f16x8*)(wp + s*32);
      acc[tt] = __builtin_amdgcn_mfma_f32_16x16x32_f16(a2[s], b, acc[tt], 0, 0, 0);
    }
  }

  // layer 3: relu + dot with W3, butterfly-reduce over the 16 col lanes
  float p[4] = {0.f,0.f,0.f,0.f};
  #pragma unroll
  for (int tt = 0; tt < 16; tt++){
    float bb = b2[tt*16 + c];
    float wv = W3[tt*16 + c];
    #pragma unroll
    for (int r = 0; r < 4; r++)
      p[r] = fmaf(fmaxf(acc[tt][r] + bb, 0.f), wv, p[r]);
  }
  #pragma unroll
  for (int m = 1; m < 16; m <<= 1){
    #pragma unroll
    for (int r = 0; r < 4; r++) p[r] += __shfl_xor(p[r], m);
  }
  if (c == 0){
    float bb = b3[0];
    #pragma unroll
    for (int r = 0; r < 4; r++)
      out[base + w*16 + 4*g + r] = p[r] + bb;
  }
}

extern "C" void kernel_launch(void* const* d_in, const int* in_sizes, int n_in,
                              void* d_out, int out_size, void* d_ws, size_t ws_size,
                              hipStream_t stream){
  if (ws_size < (size_t)WS_NEEDED) return;  // fail validation cleanly, don't fault
  const float* x      = (const float*)d_in[0];
  const int*   ei     = (const int*)  d_in[1];
  const int*   srcp   = ei;
  const int*   dstp   = ei + NE;
  const int*   fl     = (const int*)  d_in[2];
  const float* W_emd  = (const float*)d_in[3];
  const float* b_emd  = (const float*)d_in[4];
  const float* W_aggr = (const float*)d_in[5];
  const float* b_aggr = (const float*)d_in[6];
  const float* w_ih   = (const float*)d_in[7];
  const float* w_hh   = (const float*)d_in[8];
  const float* b_ih   = (const float*)d_in[9];
  const float* b_hh   = (const float*)d_in[10];
  const float* W1     = (const float*)d_in[11];
  const float* b1     = (const float*)d_in[12];
  const float* W2     = (const float*)d_in[13];
  const float* b2     = (const float*)d_in[14];
  const float* W3     = (const float*)d_in[15];
  const float* b3     = (const float*)d_in[16];

  char* ws = (char*)d_ws;
  float* h        = (float*)(ws + OFF_H);
  float* s_c      = (float*)(ws + OFF_SC);
  float* deg_c    = (float*)(ws + OFF_DEG);
  int*   node_list= (int*)  (ws + OFF_NLIST);
  int*   node_pos = (int*)  (ws + OFF_NPOS);
  int*   edge_list= (int*)  (ws + OFF_ELIST);
  float* WcT      = (float*)(ws + OFF_WCT);
  float* whhT     = (float*)(ws + OFF_WHHT);
  float* mb       = (float*)(ws + OFF_MB);
  _Float16* W1h   = (_Float16*)(ws + OFF_W1H);
  _Float16* W2h   = (_Float16*)(ws + OFF_W2H);
  int*   cnt      = (int*)  (ws + OFF_CNT);
  float* outp     = (float*)d_out;

  k_zero_cnt<<<1, 128, 0, stream>>>(cnt);
  k_init_h<<<4096, 256, 0, stream>>>(h, W_emd, b_emd);
  k_count<<<3125, 256, 0, stream>>>(fl, dstp, cnt);
  k_scan<<<1, 64, 0, stream>>>(cnt);
  k_fill_n<<<196, 256, 0, stream>>>(fl, cnt, node_list, node_pos);
  k_fill_e<<<586, 256, 0, stream>>>(fl, dstp, cnt, edge_list);
  k_prep<<<256, 256, 0, stream>>>(w_ih, W_aggr, b_aggr, w_hh, W1, W2,
                                  WcT, whhT, mb, W1h, W2h);
  for (int l = 1; l < NLVL; l++){
    k_zero_s<<<1024, 256, 0, stream>>>(cnt, l, s_c, deg_c);
    k_scatter<<<2048, 256, 0, stream>>>(cnt, l, edge_list, srcp, dstp, node_pos,
                                        h, s_c, deg_c);
    k_gru<<<1024, 256, 0, stream>>>(cnt, l, node_list, s_c, deg_c, x,
                                    WcT, whhT, mb, w_ih, b_ih, b_hh, h);
  }
  k_mlp_mfma<<<3125, 256, 0, stream>>>(h, W1h, b1, W2h, b2, W3, b3, outp);
}

// Round 5
// 1583.365 us; speedup vs baseline: 3.3280x; 1.1016x over previous
//
#include <hip/hip_runtime.h>

#define NN 200000
#define NE 600000
#define DD 128
#define DXX 3
#define DMM 256
#define NLVL 16
#define MAXLVL 16384   // max nodes per level (true ~12500, Binomial(200k,1/16))

// ---- workspace byte offsets (total ~115.6 MB) ----
#define OFF_H      0LL                      // float h[NN][128]         102,400,000
#define OFF_SC     102400000LL              // float s_c[MAXLVL][128]     8,388,608
#define OFF_DEG    110788608LL              // float deg_c[MAXLVL]           65,536
#define OFF_NLIST  110854144LL              // int node_list[NN]            800,000
#define OFF_NPOS   111654144LL              // int node_pos[NN]             800,000
#define OFF_ELIST  112454144LL              // int edge_list[NE]          2,400,000
#define OFF_WCT    114854144LL              // float WcT[128][384]          196,608
#define OFF_WHHT   115050752LL              // float whhT[128][384]         196,608
#define OFF_MB     115247360LL              // float mb[384]                  1,536
#define OFF_W1H    115248896LL              // _Float16 W1h[256][128]        65,536
#define OFF_W2H    115379968LL              // _Float16 W2h[256][256]       131,072
#define OFF_CNT    115642112LL              // int counters[128]                512
#define WS_NEEDED  115642624LL

typedef float    f32x4 __attribute__((ext_vector_type(4)));
typedef _Float16 f16x8 __attribute__((ext_vector_type(8)));
typedef _Float16 f16x4 __attribute__((ext_vector_type(4)));

__device__ __forceinline__ float sigm(float x){
  x = fminf(fmaxf(x, -30.f), 30.f);
  return 1.f/(1.f + __expf(-x));
}
__device__ __forceinline__ float tanh_(float x){
  x = fminf(fmaxf(x, -15.f), 15.f);
  float e = __expf(2.f*x);
  return (e - 1.f)/(e + 1.f);
}

__global__ void k_zero_cnt(int* cnt){
  if (threadIdx.x < 128) cnt[threadIdx.x] = 0;
}

// h[v][d] = W_emd[d] + b_emd[d] for all v
__global__ void k_init_h(float* h, const float* W_emd, const float* b_emd){
  __shared__ float h0[DD];
  if (threadIdx.x < DD) h0[threadIdx.x] = W_emd[threadIdx.x] + b_emd[threadIdx.x];
  __syncthreads();
  const int tot = NN*DD/4;
  for (int i = blockIdx.x*blockDim.x + threadIdx.x; i < tot; i += gridDim.x*blockDim.x){
    int d0 = (i & 31)*4;
    ((float4*)h)[i] = make_float4(h0[d0], h0[d0+1], h0[d0+2], h0[d0+3]);
  }
}

// histogram nodes by level, edges by dst level
__global__ void k_count(const int* fl, const int* dst, int* cnt){
  __shared__ int hn[NLVL], he[NLVL];
  if (threadIdx.x < NLVL){ hn[threadIdx.x]=0; he[threadIdx.x]=0; }
  __syncthreads();
  const int tot = NN + NE;
  for (int i = blockIdx.x*blockDim.x + threadIdx.x; i < tot; i += gridDim.x*blockDim.x){
    if (i < NN) atomicAdd(&hn[fl[i]], 1);
    else        atomicAdd(&he[fl[dst[i-NN]]], 1);
  }
  __syncthreads();
  if (threadIdx.x < NLVL){
    if (hn[threadIdx.x]) atomicAdd(&cnt[threadIdx.x], hn[threadIdx.x]);
    if (he[threadIdx.x]) atomicAdd(&cnt[16+threadIdx.x], he[threadIdx.x]);
  }
}

__global__ void k_scan(int* cnt){
  if (threadIdx.x == 0){
    int s = 0;
    for (int l=0;l<NLVL;l++){ cnt[32+l] = s; s += cnt[l]; }
    cnt[48] = s;
    s = 0;
    for (int l=0;l<NLVL;l++){ cnt[49+l] = s; s += cnt[16+l]; }
    cnt[65] = s;
    for (int l=0;l<NLVL;l++){ cnt[66+l]=0; cnt[82+l]=0; }
  }
}

// ---- counting-sort fill: LDS histogram + one global atomic per (tile,level)
#define FB 1024
__global__ __launch_bounds__(256) void k_fill_n(const int* fl, int* cnt,
                                                int* node_list, int* node_pos){
  __shared__ int hist[NLVL], base[NLVL];
  const int nt = (NN + FB - 1)/FB;
  for (int tile = blockIdx.x; tile < nt; tile += gridDim.x){
    const int i0 = tile*FB;
    if (threadIdx.x < NLVL) hist[threadIdx.x] = 0;
    __syncthreads();
    int lv[4], rk[4];
    #pragma unroll
    for (int j=0;j<4;j++){
      int i = i0 + threadIdx.x + j*256;
      if (i < NN){
        int l = fl[i];
        lv[j] = l;
        rk[j] = atomicAdd(&hist[l], 1);
      } else lv[j] = -1;
    }
    __syncthreads();
    if (threadIdx.x < NLVL)
      base[threadIdx.x] = atomicAdd(&cnt[66+threadIdx.x], hist[threadIdx.x]);
    __syncthreads();
    #pragma unroll
    for (int j=0;j<4;j++){
      if (lv[j] >= 0){
        int i = i0 + threadIdx.x + j*256;
        int p = base[lv[j]] + rk[j];
        node_list[cnt[32+lv[j]] + p] = i;
        node_pos[i] = (p < MAXLVL) ? p : (MAXLVL-1);  // clamp: OOB-safe
      }
    }
    __syncthreads();
  }
}

__global__ __launch_bounds__(256) void k_fill_e(const int* fl, const int* dst,
                                                int* cnt, int* edge_list){
  __shared__ int hist[NLVL], base[NLVL];
  const int nt = (NE + FB - 1)/FB;
  for (int tile = blockIdx.x; tile < nt; tile += gridDim.x){
    const int i0 = tile*FB;
    if (threadIdx.x < NLVL) hist[threadIdx.x] = 0;
    __syncthreads();
    int lv[4], rk[4];
    #pragma unroll
    for (int j=0;j<4;j++){
      int e = i0 + threadIdx.x + j*256;
      if (e < NE){
        int l = fl[dst[e]];
        lv[j] = l;
        rk[j] = atomicAdd(&hist[l], 1);
      } else lv[j] = -1;
    }
    __syncthreads();
    if (threadIdx.x < NLVL)
      base[threadIdx.x] = atomicAdd(&cnt[82+threadIdx.x], hist[threadIdx.x]);
    __syncthreads();
    #pragma unroll
    for (int j=0;j<4;j++){
      if (lv[j] >= 0){
        int e = i0 + threadIdx.x + j*256;
        edge_list[cnt[49+lv[j]] + base[lv[j]] + rk[j]] = e;
      }
    }
    __syncthreads();
  }
}

// Precompute WcT[k][r] = sum_j w_ih[r][j]*W_aggr[j][k]; whhT; mb; fp16 W1/W2
__global__ void k_prep(const float* w_ih, const float* W_aggr, const float* b_aggr,
                       const float* w_hh, const float* W1, const float* W2,
                       float* WcT, float* whhT, float* mb, _Float16* W1h, _Float16* W2h){
  const int tid = blockIdx.x*blockDim.x + threadIdx.x;
  const int stride = gridDim.x*blockDim.x;
  for (int i = tid; i < 384*DD; i += stride){
    int r = i >> 7, k = i & (DD-1);
    float s = 0.f;
    for (int j=0;j<DD;j++) s += w_ih[r*(DD+DXX)+j]*W_aggr[j*DD+k];
    WcT[k*384 + r] = s;
  }
  for (int i = tid; i < 384*DD; i += stride){
    int r = i >> 7, k = i & (DD-1);
    whhT[k*384 + r] = w_hh[r*DD + k];
  }
  for (int i = tid; i < 384; i += stride){
    float s = 0.f;
    for (int j=0;j<DD;j++) s += w_ih[i*(DD+DXX)+j]*b_aggr[j];
    mb[i] = s;
  }
  for (int i = tid; i < DMM*DD;  i += stride) W1h[i] = (_Float16)W1[i];
  for (int i = tid; i < DMM*DMM; i += stride) W2h[i] = (_Float16)W2[i];
}

__global__ void k_zero_s(const int* cnt, int l, float* s_c, float* deg_c){
  int na = cnt[32+l+1] - cnt[32+l];
  if (na > MAXLVL) na = MAXLVL;
  const int tot = na*DD;
  const int stride = gridDim.x*blockDim.x;
  for (int i = blockIdx.x*blockDim.x + threadIdx.x; i < tot; i += stride) s_c[i] = 0.f;
  for (int i = blockIdx.x*blockDim.x + threadIdx.x; i < na;  i += stride) deg_c[i] = 0.f;
}

// scatter-add h[src] into compact s_c rows (dst nodes of this level)
__global__ void k_scatter(const int* cnt, int l, const int* edge_list,
                          const int* srcp, const int* dstp, const int* node_pos,
                          const float* h, float* s_c, float* deg_c){
  const int e0 = cnt[49+l];
  const int ne = cnt[49+l+1] - e0;
  const int tot = ne*DD;
  const int stride = gridDim.x*blockDim.x;
  for (int i = blockIdx.x*blockDim.x + threadIdx.x; i < tot; i += stride){
    int ei = i >> 7, d = i & (DD-1);
    int e  = edge_list[e0 + ei];
    int sv = srcp[e], dv = dstp[e];
    atomicAdd(&s_c[node_pos[dv]*DD + d], h[sv*DD + d]);
    if (d == 0) atomicAdd(&deg_c[node_pos[dv]], 1.f);
  }
}

// GRU update for the level's nodes. 32 nodes/block, 256 threads.
#define GTM 32
__global__ __launch_bounds__(256) void k_gru(const int* cnt, int l,
    const int* node_list, const float* s_c, const float* deg_c,
    const float* x, const float* WcT, const float* whhT, const float* mb,
    const float* w_ih, const float* b_ih, const float* b_hh, float* h){
  const int n0 = cnt[32+l];
  int na = cnt[32+l+1] - n0;
  if (na > MAXLVL) na = MAXLVL;
  if (na <= 0) return;
  const int ntiles = (na + GTM-1)/GTM;
  __shared__ float s_l[GTM][DD];
  __shared__ float h_l[GTM][DD];
  __shared__ float x_l[GTM][4];
  __shared__ float deg_l[GTM];
  __shared__ int   vidx[GTM];
  const int t  = threadIdx.x;
  const int jt = t & (DD-1);
  const int g  = t >> 7;
  for (int tile = blockIdx.x; tile < ntiles; tile += gridDim.x){
    const int tb = tile*GTM;
    if (t < GTM){
      int v = (tb + t < na) ? node_list[n0 + tb + t] : -1;
      vidx[t] = v;
      deg_l[t] = (tb + t < na) ? deg_c[tb + t] : 0.f;
      for (int kx=0; kx<DXX; kx++) x_l[t][kx] = (v >= 0) ? x[v*DXX + kx] : 0.f;
    }
    for (int i = t; i < GTM*DD; i += 256){
      int j = i >> 7, k = i & (DD-1);
      int row = tb + j;
      float sv = 0.f, hv = 0.f;
      if (row < na){
        sv = s_c[row*DD + k];
        hv = h[node_list[n0 + row]*DD + k];
      }
      s_l[j][k] = sv;
      h_l[j][k] = hv;
    }
    __syncthreads();

    float agr[16], agz[16], agn[16], ahr[16], ahz[16], ahn[16];
    #pragma unroll
    for (int n=0;n<16;n++){ agr[n]=0.f; agz[n]=0.f; agn[n]=0.f; ahr[n]=0.f; ahz[n]=0.f; ahn[n]=0.f; }

    #pragma unroll 2
    for (int k=0;k<DD;k++){
      float w1 = WcT[k*384 + jt];
      float w2 = WcT[k*384 + 128 + jt];
      float w3 = WcT[k*384 + 256 + jt];
      float u1 = whhT[k*384 + jt];
      float u2 = whhT[k*384 + 128 + jt];
      float u3 = whhT[k*384 + 256 + jt];
      #pragma unroll
      for (int n=0;n<16;n++){
        int node = 2*n + g;
        float sv = s_l[node][k];
        float hv = h_l[node][k];
        agr[n] = fmaf(w1, sv, agr[n]);
        agz[n] = fmaf(w2, sv, agz[n]);
        agn[n] = fmaf(w3, sv, agn[n]);
        ahr[n] = fmaf(u1, hv, ahr[n]);
        ahz[n] = fmaf(u2, hv, ahz[n]);
        ahn[n] = fmaf(u3, hv, ahn[n]);
      }
    }
    #pragma unroll
    for (int kx=0;kx<DXX;kx++){
      float wx1 = w_ih[jt*(DD+DXX) + DD + kx];
      float wx2 = w_ih[(128+jt)*(DD+DXX) + DD + kx];
      float wx3 = w_ih[(256+jt)*(DD+DXX) + DD + kx];
      #pragma unroll
      for (int n=0;n<16;n++){
        int node = 2*n + g;
        float xv = x_l[node][kx];
        agr[n] = fmaf(wx1, xv, agr[n]);
        agz[n] = fmaf(wx2, xv, agz[n]);
        agn[n] = fmaf(wx3, xv, agn[n]);
      }
    }
    float bi1 = b_ih[jt], bi2 = b_ih[128+jt], bi3 = b_ih[256+jt];
    float bh1 = b_hh[jt], bh2 = b_hh[128+jt], bh3 = b_hh[256+jt];
    float m1 = mb[jt], m2 = mb[128+jt], m3 = mb[256+jt];
    #pragma unroll
    for (int n=0;n<16;n++){
      int node = 2*n + g;
      int v = vidx[node];
      if (v < 0) continue;
      float dg = deg_l[node];
      float gr = agr[n] + bi1 + dg*m1 + ahr[n] + bh1;
      float gz = agz[n] + bi2 + dg*m2 + ahz[n] + bh2;
      float rr = sigm(gr);
      float zz = sigm(gz);
      float gn = agn[n] + bi3 + dg*m3 + rr*(ahn[n] + bh3);
      float nv = tanh_(gn);
      float hv = h_l[node][jt];
      h[v*DD + jt] = (1.f - zz)*nv + zz*hv;
    }
    __syncthreads();
  }
}

// Persistent-weight MFMA MLP: h(128) -> relu 256 -> relu 256 -> 1.
// 256 blocks (1/CU), 4 waves; wave w owns output cols [64w,64w+64) of BOTH
// layers; W1/W2 fragments live in registers for the whole kernel (192 VGPR),
// eliminating the per-tile L2 weight stream that made round-4 latency-bound.
// Per 64-node tile: A-frags from global h, h1 via 32KB XOR-swizzled LDS.
// MFMA 16x16x32_f16: A lane l: row=l&15, k=8*(l>>4)+i; C/D lane l reg r:
// row=4*(l>>4)+r, col=l&15  [m89-verified].
__global__ __launch_bounds__(256, 1) void k_mlp_pw(const float* __restrict__ h,
    const _Float16* __restrict__ W1h, const float* __restrict__ b1,
    const _Float16* __restrict__ W2h, const float* __restrict__ b2,
    const float* __restrict__ W3, const float* __restrict__ b3,
    float* __restrict__ out){
  __shared__ _Float16 h1s[64*256];   // 32 KB, rows 512B, byte ^= (row&7)<<4
  __shared__ float red[4][64];
  const int t    = threadIdx.x;
  const int w    = t >> 6;
  const int lane = t & 63;
  const int c    = lane & 15;
  const int g    = lane >> 4;

  // ---- persistent weight fragments (once per block) ----
  f16x8 w1f[4][4], w2f[4][8];
  #pragma unroll
  for (int n = 0; n < 4; n++){
    const _Float16* wp = W1h + ((4*w+n)*16 + c)*DD + 8*g;
    #pragma unroll
    for (int s = 0; s < 4; s++) w1f[n][s] = *(const f16x8*)(wp + s*32);
  }
  #pragma unroll
  for (int n = 0; n < 4; n++){
    const _Float16* wp = W2h + ((4*w+n)*16 + c)*DMM + 8*g;
    #pragma unroll
    for (int s = 0; s < 8; s++) w2f[n][s] = *(const f16x8*)(wp + s*32);
  }
  float bb1[4], bb2[4], w3v[4];
  #pragma unroll
  for (int n = 0; n < 4; n++){
    bb1[n] = b1[(4*w+n)*16 + c];
    bb2[n] = b2[(4*w+n)*16 + c];
    w3v[n] = W3[(4*w+n)*16 + c];
  }
  const float b3s = b3[0];

  for (int tile = blockIdx.x; tile < NN/64; tile += gridDim.x){
    const int base = tile*64;
    // ---- A1 fragments straight from global h ----
    f16x8 a1[4][4];
    #pragma unroll
    for (int m = 0; m < 4; m++){
      const float* hp = h + (size_t)(base + m*16 + c)*DD + 8*g;
      #pragma unroll
      for (int s = 0; s < 4; s++){
        float4 u0 = *(const float4*)(hp + s*32);
        float4 u1 = *(const float4*)(hp + s*32 + 4);
        a1[m][s] = (f16x8){(_Float16)u0.x,(_Float16)u0.y,(_Float16)u0.z,(_Float16)u0.w,
                           (_Float16)u1.x,(_Float16)u1.y,(_Float16)u1.z,(_Float16)u1.w};
      }
    }
    // ---- layer 1 ----
    f32x4 acc[4][4];
    #pragma unroll
    for (int m = 0; m < 4; m++)
      #pragma unroll
      for (int n = 0; n < 4; n++) acc[m][n] = (f32x4){0.f,0.f,0.f,0.f};
    #pragma unroll
    for (int m = 0; m < 4; m++)
      #pragma unroll
      for (int n = 0; n < 4; n++)
        #pragma unroll
        for (int s = 0; s < 4; s++)
          acc[m][n] = __builtin_amdgcn_mfma_f32_16x16x32_f16(a1[m][s], w1f[n][s], acc[m][n], 0, 0, 0);
    // h1 = relu(acc+b1) -> swizzled LDS
    #pragma unroll
    for (int m = 0; m < 4; m++)
      #pragma unroll
      for (int n = 0; n < 4; n++)
        #pragma unroll
        for (int r = 0; r < 4; r++){
          int row = m*16 + 4*g + r;
          int off = (row*512 + ((4*w+n)*16 + c)*2) ^ ((row & 7) << 4);
          *(_Float16*)((char*)h1s + off) = (_Float16)fmaxf(acc[m][n][r] + bb1[n], 0.f);
        }
    __syncthreads();
    // ---- layer 2 + 3 ----
    float p[4][4];
    #pragma unroll
    for (int m = 0; m < 4; m++)
      #pragma unroll
      for (int r = 0; r < 4; r++) p[m][r] = 0.f;
    #pragma unroll
    for (int m = 0; m < 4; m++){
      f16x8 a2[8];
      int row = m*16 + c;
      #pragma unroll
      for (int s = 0; s < 8; s++){
        int off = (row*512 + s*64 + g*16) ^ ((row & 7) << 4);
        a2[s] = *(const f16x8*)((const char*)h1s + off);
      }
      f32x4 acc2[4];
      #pragma unroll
      for (int n = 0; n < 4; n++) acc2[n] = (f32x4){0.f,0.f,0.f,0.f};
      #pragma unroll
      for (int n = 0; n < 4; n++)
        #pragma unroll
        for (int s = 0; s < 8; s++)
          acc2[n] = __builtin_amdgcn_mfma_f32_16x16x32_f16(a2[s], w2f[n][s], acc2[n], 0, 0, 0);
      #pragma unroll
      for (int n = 0; n < 4; n++)
        #pragma unroll
        for (int r = 0; r < 4; r++)
          p[m][r] = fmaf(fmaxf(acc2[n][r] + bb2[n], 0.f), w3v[n], p[m][r]);
    }
    // reduce across the 16 col-lanes (low 4 lane bits)
    #pragma unroll
    for (int msk = 1; msk < 16; msk <<= 1)
      #pragma unroll
      for (int m = 0; m < 4; m++)
        #pragma unroll
        for (int r = 0; r < 4; r++)
          p[m][r] += __shfl_xor(p[m][r], msk);
    if (c == 0){
      #pragma unroll
      for (int m = 0; m < 4; m++)
        #pragma unroll
        for (int r = 0; r < 4; r++)
          red[w][m*16 + 4*g + r] = p[m][r];
    }
    __syncthreads();
    if (t < 64)
      out[base + t] = red[0][t] + red[1][t] + red[2][t] + red[3][t] + b3s;
  }
}

extern "C" void kernel_launch(void* const* d_in, const int* in_sizes, int n_in,
                              void* d_out, int out_size, void* d_ws, size_t ws_size,
                              hipStream_t stream){
  if (ws_size < (size_t)WS_NEEDED) return;  // fail validation cleanly, don't fault
  const float* x      = (const float*)d_in[0];
  const int*   ei     = (const int*)  d_in[1];
  const int*   srcp   = ei;
  const int*   dstp   = ei + NE;
  const int*   fl     = (const int*)  d_in[2];
  const float* W_emd  = (const float*)d_in[3];
  const float* b_emd  = (const float*)d_in[4];
  const float* W_aggr = (const float*)d_in[5];
  const float* b_aggr = (const float*)d_in[6];
  const float* w_ih   = (const float*)d_in[7];
  const float* w_hh   = (const float*)d_in[8];
  const float* b_ih   = (const float*)d_in[9];
  const float* b_hh   = (const float*)d_in[10];
  const float* W1     = (const float*)d_in[11];
  const float* b1     = (const float*)d_in[12];
  const float* W2     = (const float*)d_in[13];
  const float* b2     = (const float*)d_in[14];
  const float* W3     = (const float*)d_in[15];
  const float* b3     = (const float*)d_in[16];

  char* ws = (char*)d_ws;
  float* h        = (float*)(ws + OFF_H);
  float* s_c      = (float*)(ws + OFF_SC);
  float* deg_c    = (float*)(ws + OFF_DEG);
  int*   node_list= (int*)  (ws + OFF_NLIST);
  int*   node_pos = (int*)  (ws + OFF_NPOS);
  int*   edge_list= (int*)  (ws + OFF_ELIST);
  float* WcT      = (float*)(ws + OFF_WCT);
  float* whhT     = (float*)(ws + OFF_WHHT);
  float* mb       = (float*)(ws + OFF_MB);
  _Float16* W1h   = (_Float16*)(ws + OFF_W1H);
  _Float16* W2h   = (_Float16*)(ws + OFF_W2H);
  int*   cnt      = (int*)  (ws + OFF_CNT);
  float* outp     = (float*)d_out;

  k_zero_cnt<<<1, 128, 0, stream>>>(cnt);
  k_init_h<<<4096, 256, 0, stream>>>(h, W_emd, b_emd);
  k_count<<<3125, 256, 0, stream>>>(fl, dstp, cnt);
  k_scan<<<1, 64, 0, stream>>>(cnt);
  k_fill_n<<<196, 256, 0, stream>>>(fl, cnt, node_list, node_pos);
  k_fill_e<<<586, 256, 0, stream>>>(fl, dstp, cnt, edge_list);
  k_prep<<<256, 256, 0, stream>>>(w_ih, W_aggr, b_aggr, w_hh, W1, W2,
                                  WcT, whhT, mb, W1h, W2h);
  for (int l = 1; l < NLVL; l++){
    k_zero_s<<<1024, 256, 0, stream>>>(cnt, l, s_c, deg_c);
    k_scatter<<<2048, 256, 0, stream>>>(cnt, l, edge_list, srcp, dstp, node_pos,
                                        h, s_c, deg_c);
    k_gru<<<1024, 256, 0, stream>>>(cnt, l, node_list, s_c, deg_c, x,
                                    WcT, whhT, mb, w_ih, b_ih, b_hh, h);
  }
  k_mlp_pw<<<256, 256, 0, stream>>>(h, W1h, b1, W2h, b2, W3, b3, outp);
}